// Round 8
// baseline (404.840 us; speedup 1.0000x reference)
//
#include <hip/hip_runtime.h>
#include <stdint.h>

#define N_NODES 50000
#define E_EDGES 600000
#define D 128
#define R_REL 8
#define B_BASES 10
#define RN (R_REL * N_NODES)

typedef __attribute__((ext_vector_type(8))) short bf16x8;
typedef __attribute__((ext_vector_type(4))) float f32x4;

__device__ __forceinline__ short f2b(float f) {
    uint32_t u = __float_as_uint(f);
    u += 0x7fff + ((u >> 16) & 1);   // RNE
    return (short)(u >> 16);
}
__device__ __forceinline__ float b2f(uint16_t u) {
    return __uint_as_float((uint32_t)u << 16);
}

// ---- front: x->bf16 convert + (dst,rel) histogram + weight prep, one launch ----
__global__ __launch_bounds__(256) void k_front(const float* __restrict__ x,
                                               unsigned short* __restrict__ xb,
                                               const int* __restrict__ dst,
                                               const int* __restrict__ et,
                                               int* __restrict__ cntr,
                                               const float* __restrict__ basis,
                                               const float* __restrict__ comp,
                                               const float* __restrict__ root,
                                               const float* __restrict__ wrel,
                                               const float* __restrict__ wroot,
                                               short* __restrict__ wt,
                                               short* __restrict__ wrel_b,
                                               short* __restrict__ wroot_b) {
    const int XB_N = N_NODES * D / 8;   // 800000
    int tid = blockIdx.x * 256 + threadIdx.x;
    if (tid < XB_N) {
        const float4* s = (const float4*)x + (size_t)tid * 2;
        float4 v0 = s[0], v1 = s[1];
        union { uint4 u; unsigned short h[8]; } pk;
        pk.h[0] = (unsigned short)f2b(v0.x); pk.h[1] = (unsigned short)f2b(v0.y);
        pk.h[2] = (unsigned short)f2b(v0.z); pk.h[3] = (unsigned short)f2b(v0.w);
        pk.h[4] = (unsigned short)f2b(v1.x); pk.h[5] = (unsigned short)f2b(v1.y);
        pk.h[6] = (unsigned short)f2b(v1.z); pk.h[7] = (unsigned short)f2b(v1.w);
        ((uint4*)xb)[tid] = pk.u;
    } else if (tid < XB_N + E_EDGES) {
        int e = tid - XB_N;
        atomicAdd(&cntr[dst[e] * R_REL + et[e]], 1);
    } else {
        int t2 = tid - XB_N - E_EDGES;
        if (t2 < 9 * D * D) {
            int s = t2 >> 14;
            int rem = t2 & 16383;
            int j = rem >> 7, i = rem & 127;
            float v;
            if (s < 8) {
                v = 0.f;
#pragma unroll
                for (int b = 0; b < B_BASES; b++)
                    v += comp[s * B_BASES + b] * basis[b * D * D + i * D + j];
            } else {
                v = root[i * D + j];
            }
            wt[t2] = f2b(v);
        } else {
            int t3 = t2 - 9 * D * D;
            if (t3 < D * D) {
                wrel_b[t3]  = f2b(wrel[t3]);
                wroot_b[t3] = f2b(wroot[t3]);
            }
        }
    }
}

// ---- shuffle-based block scan (1024 thr); doubles as level-2 when bsum==null ----
__device__ __forceinline__ int wave_scan_incl(int v) {
    int lane = threadIdx.x & 63;
#pragma unroll
    for (int off = 1; off < 64; off <<= 1) {
        int n = __shfl_up(v, off, 64);
        if (lane >= off) v += n;
    }
    return v;
}

__global__ __launch_bounds__(1024) void k_scan_a(const int* __restrict__ in,
                                                 int* __restrict__ out,
                                                 int* __restrict__ bsum, int n) {
    __shared__ int wsum[16];
    int t = threadIdx.x, lane = t & 63, wid = t >> 6;
    int g = blockIdx.x * 1024 + t;
    int v = (g < n) ? in[g] : 0;
    int isc = wave_scan_incl(v);
    if (lane == 63) wsum[wid] = isc;
    __syncthreads();
    if (wid == 0) {
        int wv = (lane < 16) ? wsum[lane] : 0;
        int wsc = wave_scan_incl(wv);
        if (lane < 16) wsum[lane] = wsc - wv;
    }
    __syncthreads();
    if (g < n) out[g] = wsum[wid] + isc - v;
    if (t == 1023 && bsum) bsum[blockIdx.x] = wsum[15] + isc;
}

__global__ __launch_bounds__(1024) void k_scan_c(int* __restrict__ out,
                                                 const int* __restrict__ bsum, int n) {
    int g = blockIdx.x * 1024 + threadIdx.x;
    if (g < n) out[g] += bsum[blockIdx.x];
}

// ---- bucket: es1[pos] = src, sorted by (dst,rel); bumps seg_off to segment ENDS ----
__global__ __launch_bounds__(256) void k_bucket(const int* __restrict__ src,
                                                const int* __restrict__ dst,
                                                const int* __restrict__ et,
                                                int* __restrict__ seg_off,
                                                int* __restrict__ es1) {
    int e = blockIdx.x * 256 + threadIdx.x;
    if (e >= E_EDGES) return;
    int key = dst[e] * R_REL + et[e];
    int pos = atomicAdd(&seg_off[key], 1);
    es1[pos] = src[e];
}

// ---- per-(dst,rel) mean of xb[src] -> mx bf16.  One 16-lane subwave / segment ----
__global__ __launch_bounds__(256) void k_aggmean(const unsigned short* __restrict__ xb,
                                                 const int* __restrict__ es1,
                                                 const int* __restrict__ seg_off,
                                                 unsigned short* __restrict__ mx) {
    int t = threadIdx.x;
    int sw = t >> 4, l = t & 15;
    int k = blockIdx.x * 16 + sw;
    if (k >= RN) return;
    int start = (k == 0) ? 0 : seg_off[k - 1];
    int end = seg_off[k];
    float ax[8];
#pragma unroll
    for (int q = 0; q < 8; q++) ax[q] = 0.f;
    size_t loff = (size_t)l * 8;
    int pos = start;
    for (; pos + 2 <= end; pos += 2) {
        int s0 = es1[pos], s1 = es1[pos + 1];
        uint4 v0 = *(const uint4*)(xb + (size_t)s0 * D + loff);
        uint4 v1 = *(const uint4*)(xb + (size_t)s1 * D + loff);
        const uint32_t* w0 = (const uint32_t*)&v0;
        const uint32_t* w1 = (const uint32_t*)&v1;
#pragma unroll
        for (int q = 0; q < 4; q++) {
            ax[q * 2]     += b2f((uint16_t)w0[q]) + b2f((uint16_t)w1[q]);
            ax[q * 2 + 1] += b2f((uint16_t)(w0[q] >> 16)) + b2f((uint16_t)(w1[q] >> 16));
        }
    }
    if (pos < end) {
        int s0 = es1[pos];
        uint4 v0 = *(const uint4*)(xb + (size_t)s0 * D + loff);
        const uint32_t* w0 = (const uint32_t*)&v0;
#pragma unroll
        for (int q = 0; q < 4; q++) {
            ax[q * 2]     += b2f((uint16_t)w0[q]);
            ax[q * 2 + 1] += b2f((uint16_t)(w0[q] >> 16));
        }
    }
    float nm = (end > start) ? 1.f / (float)(end - start) : 0.f;
    union { uint4 u; unsigned short h[8]; } pk;
#pragma unroll
    for (int q = 0; q < 8; q++) pk.h[q] = (unsigned short)f2b(ax[q] * nm);
    *(uint4*)(mx + (size_t)k * D + loff) = pk.u;   // k*128 = d*1024 + r*128
}

// ---- h1 GEMM, barrier-free: fragments straight from global (L1 reuse) ----
// h1b[n] = bf16( sum_s A_s[n] @ wt[s] + bias1 ),  A_s = mx slice s (s<8) or xb (s=8)
__global__ __launch_bounds__(256) void k_h1_gemm(const unsigned short* __restrict__ mx,
                                                 const unsigned short* __restrict__ xb,
                                                 const short* __restrict__ wt,
                                                 const float* __restrict__ bias1,
                                                 unsigned short* __restrict__ h1b) {
    int t = threadIdx.x;
    int wave = t >> 6, lane = t & 63, quad = lane >> 4, l16 = lane & 15;
    int arow_idx = blockIdx.x * 64 + wave * 16 + l16;   // A-fragment row (node)
    bool valid = arow_idx < N_NODES;
    int nodeC = valid ? arow_idx : N_NODES - 1;
    f32x4 acc[8];
#pragma unroll
    for (int jt = 0; jt < 8; jt++) acc[jt] = (f32x4){0.f, 0.f, 0.f, 0.f};

    for (int s = 0; s < 9; s++) {
        const unsigned short* arow = (s < 8) ? mx + ((size_t)nodeC * 8 + s) * D
                                             : xb + (size_t)nodeC * D;
        const short* wbase = wt + (size_t)s * D * D;
#pragma unroll
        for (int kc = 0; kc < 4; kc++) {
            int c0 = kc * 4 + quad;
            bf16x8 a = (bf16x8){0, 0, 0, 0, 0, 0, 0, 0};
            if (valid) a = *(const bf16x8*)(arow + c0 * 8);
#pragma unroll
            for (int jt = 0; jt < 8; jt++) {
                bf16x8 b = *(const bf16x8*)(wbase + (jt * 16 + l16) * D + c0 * 8);
                acc[jt] = __builtin_amdgcn_mfma_f32_16x16x32_bf16(a, b, acc[jt], 0, 0, 0);
            }
        }
    }

#pragma unroll
    for (int reg = 0; reg < 4; reg++) {
        int node = blockIdx.x * 64 + wave * 16 + quad * 4 + reg;
        if (node >= N_NODES) continue;
#pragma unroll
        for (int jt = 0; jt < 8; jt++) {
            int col = jt * 16 + l16;
            float v = acc[jt][reg] + bias1[col];
            h1b[(size_t)node * D + col] = (unsigned short)f2b(v);
        }
    }
}

// ---- GraphConv agg: nbr[d] = sum h1b[src] over full in-edge range (16-lane subwave) ----
__global__ __launch_bounds__(256) void k_agg_nbr(const unsigned short* __restrict__ h1b,
                                                 const int* __restrict__ es1,
                                                 const int* __restrict__ seg_off,
                                                 unsigned short* __restrict__ nbr) {
    int t = threadIdx.x;
    int wave = t >> 6, lane = t & 63, sub = lane >> 4, l = lane & 15;
    int d = blockIdx.x * 16 + wave * 4 + sub;
    if (d >= N_NODES) return;
    int start = (d == 0) ? 0 : seg_off[d * R_REL - 1];
    int end = seg_off[d * R_REL + 7];
    float acc[8];
#pragma unroll
    for (int j = 0; j < 8; j++) acc[j] = 0.f;
    size_t loff = (size_t)l * 8;

    int pos = start;
    for (; pos + 4 <= end; pos += 4) {
        int i0 = es1[pos], i1 = es1[pos + 1], i2 = es1[pos + 2], i3 = es1[pos + 3];
        uint4 v0 = *(const uint4*)(h1b + (size_t)i0 * D + loff);
        uint4 v1 = *(const uint4*)(h1b + (size_t)i1 * D + loff);
        uint4 v2 = *(const uint4*)(h1b + (size_t)i2 * D + loff);
        uint4 v3 = *(const uint4*)(h1b + (size_t)i3 * D + loff);
        const uint32_t* w0 = (const uint32_t*)&v0;
        const uint32_t* w1 = (const uint32_t*)&v1;
        const uint32_t* w2 = (const uint32_t*)&v2;
        const uint32_t* w3 = (const uint32_t*)&v3;
#pragma unroll
        for (int q = 0; q < 4; q++) {
            acc[q * 2]     += b2f((uint16_t)w0[q]) + b2f((uint16_t)w1[q]) +
                              b2f((uint16_t)w2[q]) + b2f((uint16_t)w3[q]);
            acc[q * 2 + 1] += b2f((uint16_t)(w0[q] >> 16)) + b2f((uint16_t)(w1[q] >> 16)) +
                              b2f((uint16_t)(w2[q] >> 16)) + b2f((uint16_t)(w3[q] >> 16));
        }
    }
    for (; pos < end; pos++) {
        int i0 = es1[pos];
        uint4 v0 = *(const uint4*)(h1b + (size_t)i0 * D + loff);
        const uint32_t* w0 = (const uint32_t*)&v0;
#pragma unroll
        for (int q = 0; q < 4; q++) {
            acc[q * 2]     += b2f((uint16_t)w0[q]);
            acc[q * 2 + 1] += b2f((uint16_t)(w0[q] >> 16));
        }
    }

    union { uint4 u; unsigned short h[8]; } pk;
#pragma unroll
    for (int j = 0; j < 8; j++) pk.h[j] = (unsigned short)f2b(acc[j]);
    *(uint4*)(nbr + (size_t)d * D + loff) = pk.u;
}

// ---- epilogue GEMM, barrier-free: out = h1b@wroot^T + nbr@wrel^T + brel ----
__global__ __launch_bounds__(256) void k_out2(const unsigned short* __restrict__ h1b,
                                              const unsigned short* __restrict__ nbr,
                                              const short* __restrict__ wroot_b,
                                              const short* __restrict__ wrel_b,
                                              const float* __restrict__ brel,
                                              float* __restrict__ out) {
    int t = threadIdx.x;
    int wave = t >> 6, lane = t & 63, quad = lane >> 4, l16 = lane & 15;
    int arow_idx = blockIdx.x * 64 + wave * 16 + l16;
    bool valid = arow_idx < N_NODES;
    int nodeC = valid ? arow_idx : N_NODES - 1;
    f32x4 acc[8];
#pragma unroll
    for (int jt = 0; jt < 8; jt++) acc[jt] = (f32x4){0.f, 0.f, 0.f, 0.f};

#pragma unroll
    for (int pass = 0; pass < 2; pass++) {
        const unsigned short* arow = (pass == 0 ? h1b : nbr) + (size_t)nodeC * D;
        const short* wbase = pass == 0 ? wroot_b : wrel_b;
#pragma unroll
        for (int kc = 0; kc < 4; kc++) {
            int c0 = kc * 4 + quad;
            bf16x8 a = (bf16x8){0, 0, 0, 0, 0, 0, 0, 0};
            if (valid) a = *(const bf16x8*)(arow + c0 * 8);
#pragma unroll
            for (int jt = 0; jt < 8; jt++) {
                bf16x8 b = *(const bf16x8*)(wbase + (jt * 16 + l16) * D + c0 * 8);
                acc[jt] = __builtin_amdgcn_mfma_f32_16x16x32_bf16(a, b, acc[jt], 0, 0, 0);
            }
        }
    }

#pragma unroll
    for (int reg = 0; reg < 4; reg++) {
        int node = blockIdx.x * 64 + wave * 16 + quad * 4 + reg;
        if (node >= N_NODES) continue;
#pragma unroll
        for (int jt = 0; jt < 8; jt++) {
            int col = jt * 16 + l16;
            out[(size_t)node * D + col] = acc[jt][reg] + brel[col];
        }
    }
}

extern "C" void kernel_launch(void* const* d_in, const int* in_sizes, int n_in,
                              void* d_out, int out_size, void* d_ws, size_t ws_size,
                              hipStream_t stream) {
    const float* x     = (const float*)d_in[0];
    const int*   ei    = (const int*)d_in[1];
    const int*   et    = (const int*)d_in[2];
    const float* basis = (const float*)d_in[3];
    const float* comp  = (const float*)d_in[4];
    const float* root  = (const float*)d_in[5];
    const float* bias1 = (const float*)d_in[6];
    const float* wrel  = (const float*)d_in[7];
    const float* brel  = (const float*)d_in[8];
    const float* wroot = (const float*)d_in[9];
    float* out = (float*)d_out;
    const int* src = ei;
    const int* dst = ei + E_EDGES;

    char* p = (char*)d_ws;
    auto alloc = [&](size_t bytes) { char* q = p; p += (bytes + 255) & ~(size_t)255; return q; };
    short* wt      = (short*)alloc((size_t)9 * D * D * sizeof(short));
    short* wrel_b  = (short*)alloc(D * D * sizeof(short));
    short* wroot_b = (short*)alloc(D * D * sizeof(short));
    int*   cntr    = (int*)alloc((size_t)RN * sizeof(int));
    int*   seg_off = (int*)alloc((size_t)RN * sizeof(int));
    int*   es1     = (int*)alloc((size_t)(E_EDGES + 16) * sizeof(int));
    int*   bsum    = (int*)alloc(1024 * sizeof(int));
    unsigned short* xb  = (unsigned short*)alloc((size_t)N_NODES * D * sizeof(unsigned short));
    unsigned short* mx  = (unsigned short*)alloc((size_t)RN * D * sizeof(unsigned short));
    unsigned short* h1b = (unsigned short*)alloc((size_t)N_NODES * D * sizeof(unsigned short));
    unsigned short* nbr = xb;   // xb dead after k_h1_gemm; reuse for nbr

    hipMemsetAsync(cntr, 0, (size_t)RN * sizeof(int), stream);

    const int XB_N = N_NODES * D / 8;
    int nfront = (XB_N + E_EDGES + 9 * D * D + D * D + 255) / 256;
    k_front<<<nfront, 256, 0, stream>>>(x, xb, dst, et, cntr,
                                        basis, comp, root, wrel, wroot,
                                        wt, wrel_b, wroot_b);

    int nscan = (RN + 1023) / 1024;   // 391
    k_scan_a<<<nscan, 1024, 0, stream>>>(cntr, seg_off, bsum, RN);
    k_scan_a<<<1, 1024, 0, stream>>>(bsum, bsum, nullptr, nscan);
    k_scan_c<<<nscan, 1024, 0, stream>>>(seg_off, bsum, RN);

    k_bucket<<<(E_EDGES + 255) / 256, 256, 0, stream>>>(src, dst, et, seg_off, es1);

    k_aggmean<<<RN / 16, 256, 0, stream>>>(xb, es1, seg_off, mx);

    int nb = (N_NODES + 63) / 64;     // 782
    int na = (N_NODES + 15) / 16;     // 3125
    k_h1_gemm<<<nb, 256, 0, stream>>>(mx, xb, wt, bias1, h1b);
    k_agg_nbr<<<na, 256, 0, stream>>>(h1b, es1, seg_off, nbr);
    k_out2<<<nb, 256, 0, stream>>>(h1b, nbr, wroot_b, wrel_b, brel, out);
}

// Round 9
// 273.267 us; speedup vs baseline: 1.4815x; 1.4815x over previous
//
#include <hip/hip_runtime.h>
#include <stdint.h>

#define N_NODES 50000
#define E_EDGES 600000
#define D 128
#define R_REL 8
#define B_BASES 10
#define RN (R_REL * N_NODES)

typedef __attribute__((ext_vector_type(8))) short bf16x8;
typedef __attribute__((ext_vector_type(4))) float f32x4;

__device__ __forceinline__ short f2b(float f) {
    uint32_t u = __float_as_uint(f);
    u += 0x7fff + ((u >> 16) & 1);   // RNE
    return (short)(u >> 16);
}
__device__ __forceinline__ float b2f(uint16_t u) {
    return __uint_as_float((uint32_t)u << 16);
}

// ---- front: x->bf16 convert + (dst,rel) histogram + weight prep, one launch ----
__global__ __launch_bounds__(256) void k_front(const float* __restrict__ x,
                                               unsigned short* __restrict__ xb,
                                               const int* __restrict__ dst,
                                               const int* __restrict__ et,
                                               int* __restrict__ cntr,
                                               const float* __restrict__ basis,
                                               const float* __restrict__ comp,
                                               const float* __restrict__ root,
                                               const float* __restrict__ wrel,
                                               const float* __restrict__ wroot,
                                               short* __restrict__ wt,
                                               short* __restrict__ wrel_b,
                                               short* __restrict__ wroot_b) {
    const int XB_N = N_NODES * D / 8;   // 800000
    int tid = blockIdx.x * 256 + threadIdx.x;
    if (tid < XB_N) {
        const float4* s = (const float4*)x + (size_t)tid * 2;
        float4 v0 = s[0], v1 = s[1];
        union { uint4 u; unsigned short h[8]; } pk;
        pk.h[0] = (unsigned short)f2b(v0.x); pk.h[1] = (unsigned short)f2b(v0.y);
        pk.h[2] = (unsigned short)f2b(v0.z); pk.h[3] = (unsigned short)f2b(v0.w);
        pk.h[4] = (unsigned short)f2b(v1.x); pk.h[5] = (unsigned short)f2b(v1.y);
        pk.h[6] = (unsigned short)f2b(v1.z); pk.h[7] = (unsigned short)f2b(v1.w);
        ((uint4*)xb)[tid] = pk.u;
    } else if (tid < XB_N + E_EDGES) {
        int e = tid - XB_N;
        atomicAdd(&cntr[dst[e] * R_REL + et[e]], 1);
    } else {
        int t2 = tid - XB_N - E_EDGES;
        if (t2 < 9 * D * D) {
            int s = t2 >> 14;
            int rem = t2 & 16383;
            int j = rem >> 7, i = rem & 127;
            float v;
            if (s < 8) {
                v = 0.f;
#pragma unroll
                for (int b = 0; b < B_BASES; b++)
                    v += comp[s * B_BASES + b] * basis[b * D * D + i * D + j];
            } else {
                v = root[i * D + j];
            }
            wt[t2] = f2b(v);
        } else {
            int t3 = t2 - 9 * D * D;
            if (t3 < D * D) {
                wrel_b[t3]  = f2b(wrel[t3]);
                wroot_b[t3] = f2b(wroot[t3]);
            }
        }
    }
}

// ---- shuffle-based block scan (1024 thr); doubles as level-2 when bsum==null ----
__device__ __forceinline__ int wave_scan_incl(int v) {
    int lane = threadIdx.x & 63;
#pragma unroll
    for (int off = 1; off < 64; off <<= 1) {
        int n = __shfl_up(v, off, 64);
        if (lane >= off) v += n;
    }
    return v;
}

__global__ __launch_bounds__(1024) void k_scan_a(const int* __restrict__ in,
                                                 int* __restrict__ out,
                                                 int* __restrict__ bsum, int n) {
    __shared__ int wsum[16];
    int t = threadIdx.x, lane = t & 63, wid = t >> 6;
    int g = blockIdx.x * 1024 + t;
    int v = (g < n) ? in[g] : 0;
    int isc = wave_scan_incl(v);
    if (lane == 63) wsum[wid] = isc;
    __syncthreads();
    if (wid == 0) {
        int wv = (lane < 16) ? wsum[lane] : 0;
        int wsc = wave_scan_incl(wv);
        if (lane < 16) wsum[lane] = wsc - wv;
    }
    __syncthreads();
    if (g < n) out[g] = wsum[wid] + isc - v;
    if (t == 1023 && bsum) bsum[blockIdx.x] = wsum[15] + isc;
}

__global__ __launch_bounds__(1024) void k_scan_c(int* __restrict__ out,
                                                 const int* __restrict__ bsum, int n) {
    int g = blockIdx.x * 1024 + threadIdx.x;
    if (g < n) out[g] += bsum[blockIdx.x];
}

// ---- bucket: es1[pos] = src, sorted by (dst,rel); bumps seg_off to segment ENDS ----
__global__ __launch_bounds__(256) void k_bucket(const int* __restrict__ src,
                                                const int* __restrict__ dst,
                                                const int* __restrict__ et,
                                                int* __restrict__ seg_off,
                                                int* __restrict__ es1) {
    int e = blockIdx.x * 256 + threadIdx.x;
    if (e >= E_EDGES) return;
    int key = dst[e] * R_REL + et[e];
    int pos = atomicAdd(&seg_off[key], 1);
    es1[pos] = src[e];
}

// ---- per-(dst,rel) mean of xb[src] -> mx bf16.  One 16-lane subwave / segment ----
__global__ __launch_bounds__(256) void k_aggmean(const unsigned short* __restrict__ xb,
                                                 const int* __restrict__ es1,
                                                 const int* __restrict__ seg_off,
                                                 unsigned short* __restrict__ mx) {
    int t = threadIdx.x;
    int sw = t >> 4, l = t & 15;
    int k = blockIdx.x * 16 + sw;
    if (k >= RN) return;
    int start = (k == 0) ? 0 : seg_off[k - 1];
    int end = seg_off[k];
    float ax[8];
#pragma unroll
    for (int q = 0; q < 8; q++) ax[q] = 0.f;
    size_t loff = (size_t)l * 8;
    int pos = start;
    for (; pos + 2 <= end; pos += 2) {
        int s0 = es1[pos], s1 = es1[pos + 1];
        uint4 v0 = *(const uint4*)(xb + (size_t)s0 * D + loff);
        uint4 v1 = *(const uint4*)(xb + (size_t)s1 * D + loff);
        const uint32_t* w0 = (const uint32_t*)&v0;
        const uint32_t* w1 = (const uint32_t*)&v1;
#pragma unroll
        for (int q = 0; q < 4; q++) {
            ax[q * 2]     += b2f((uint16_t)w0[q]) + b2f((uint16_t)w1[q]);
            ax[q * 2 + 1] += b2f((uint16_t)(w0[q] >> 16)) + b2f((uint16_t)(w1[q] >> 16));
        }
    }
    if (pos < end) {
        int s0 = es1[pos];
        uint4 v0 = *(const uint4*)(xb + (size_t)s0 * D + loff);
        const uint32_t* w0 = (const uint32_t*)&v0;
#pragma unroll
        for (int q = 0; q < 4; q++) {
            ax[q * 2]     += b2f((uint16_t)w0[q]);
            ax[q * 2 + 1] += b2f((uint16_t)(w0[q] >> 16));
        }
    }
    float nm = (end > start) ? 1.f / (float)(end - start) : 0.f;
    union { uint4 u; unsigned short h[8]; } pk;
#pragma unroll
    for (int q = 0; q < 8; q++) pk.h[q] = (unsigned short)f2b(ax[q] * nm);
    *(uint4*)(mx + (size_t)k * D + loff) = pk.u;   // k*128 = d*1024 + r*128
}

// ---- h1 GEMM, software-pipelined: B dbuf in LDS, A prefetched in regs ----
// h1b[n] = bf16( sum_s A_s[n] @ wt[s] + bias1 ),  A_s = mx slice s (s<8) or xb (s=8)
__global__ __launch_bounds__(256) void k_h1_gemm(const unsigned short* __restrict__ mx,
                                                 const unsigned short* __restrict__ xb,
                                                 const short* __restrict__ wt,
                                                 const float* __restrict__ bias1,
                                                 unsigned short* __restrict__ h1b) {
    __shared__ short ws[2][128 * 128];
    int t = threadIdx.x;
    int wave = t >> 6, lane = t & 63, quad = lane >> 4, l16 = lane & 15;
    int arow_idx = blockIdx.x * 64 + wave * 16 + l16;
    int nodeC = arow_idx < N_NODES ? arow_idx : N_NODES - 1;
    int ci0 = wave * 8;   // this wave's 8 staging chunks (1 KB each)

    const unsigned short* arow_s[9];
#pragma unroll
    for (int s = 0; s < 8; s++) arow_s[s] = mx + ((size_t)nodeC * 8 + s) * D;
    arow_s[8] = xb + (size_t)nodeC * D;

    // prologue: stage B0, prefetch A0 & A1
    uint4 aReg[2][4];
    {
        uint4 b0[8];
#pragma unroll
        for (int i = 0; i < 8; i++) {
            int row = (ci0 + i) * 4 + quad;
            b0[i] = *(const uint4*)(wt + row * D + (l16 << 3));
        }
#pragma unroll
        for (int kc = 0; kc < 4; kc++) {
            aReg[0][kc] = *(const uint4*)(arow_s[0] + (kc * 4 + quad) * 8);
            aReg[1][kc] = *(const uint4*)(arow_s[1] + (kc * 4 + quad) * 8);
        }
#pragma unroll
        for (int i = 0; i < 8; i++) {
            int row = (ci0 + i) * 4 + quad;
            *(uint4*)&ws[0][row * 128 + ((l16 ^ (row & 15)) << 3)] = b0[i];
        }
    }
    __syncthreads();

    f32x4 acc[8];
#pragma unroll
    for (int jt = 0; jt < 8; jt++) acc[jt] = (f32x4){0.f, 0.f, 0.f, 0.f};

    for (int s = 0; s < 9; s++) {
        int cur = s & 1;
        // (a) issue B(s+1) loads first — latency overlaps the MFMA below
        uint4 bn[8];
        if (s + 1 < 9) {
            const short* wb = wt + (size_t)(s + 1) * D * D;
#pragma unroll
            for (int i = 0; i < 8; i++) {
                int row = (ci0 + i) * 4 + quad;
                bn[i] = *(const uint4*)(wb + row * D + (l16 << 3));
            }
        }
        // (b) compute pass s from LDS buf[cur] + A regs
#pragma unroll
        for (int kc = 0; kc < 4; kc++) {
            int c0 = kc * 4 + quad;
            bf16x8 a = *(bf16x8*)&aReg[cur][kc];
#pragma unroll
            for (int jt = 0; jt < 8; jt++) {
                bf16x8 b = *(const bf16x8*)&ws[cur][(jt * 16 + l16) * 128 + ((c0 ^ l16) << 3)];
                acc[jt] = __builtin_amdgcn_mfma_f32_16x16x32_bf16(a, b, acc[jt], 0, 0, 0);
            }
        }
        // (c) prefetch A(s+2) into the register slot just freed
        if (s + 2 <= 8) {
            const unsigned short* ar = arow_s[s + 2];
#pragma unroll
            for (int kc = 0; kc < 4; kc++)
                aReg[cur][kc] = *(const uint4*)(ar + (kc * 4 + quad) * 8);
        }
        // (d) commit B(s+1) into the other buffer
        if (s + 1 < 9) {
#pragma unroll
            for (int i = 0; i < 8; i++) {
                int row = (ci0 + i) * 4 + quad;
                *(uint4*)&ws[cur ^ 1][row * 128 + ((l16 ^ (row & 15)) << 3)] = bn[i];
            }
        }
        __syncthreads();
    }

#pragma unroll
    for (int reg = 0; reg < 4; reg++) {
        int node = blockIdx.x * 64 + wave * 16 + quad * 4 + reg;
        if (node >= N_NODES) continue;
#pragma unroll
        for (int jt = 0; jt < 8; jt++) {
            int col = jt * 16 + l16;
            float v = acc[jt][reg] + bias1[col];
            h1b[(size_t)node * D + col] = (unsigned short)f2b(v);
        }
    }
}

// ---- GraphConv agg: nbr[d] = sum h1b[src] over full in-edge range (16-lane subwave) ----
__global__ __launch_bounds__(256) void k_agg_nbr(const unsigned short* __restrict__ h1b,
                                                 const int* __restrict__ es1,
                                                 const int* __restrict__ seg_off,
                                                 unsigned short* __restrict__ nbr) {
    int t = threadIdx.x;
    int wave = t >> 6, lane = t & 63, sub = lane >> 4, l = lane & 15;
    int d = blockIdx.x * 16 + wave * 4 + sub;
    if (d >= N_NODES) return;
    int start = (d == 0) ? 0 : seg_off[d * R_REL - 1];
    int end = seg_off[d * R_REL + 7];
    float acc[8];
#pragma unroll
    for (int j = 0; j < 8; j++) acc[j] = 0.f;
    size_t loff = (size_t)l * 8;

    int pos = start;
    for (; pos + 4 <= end; pos += 4) {
        int i0 = es1[pos], i1 = es1[pos + 1], i2 = es1[pos + 2], i3 = es1[pos + 3];
        uint4 v0 = *(const uint4*)(h1b + (size_t)i0 * D + loff);
        uint4 v1 = *(const uint4*)(h1b + (size_t)i1 * D + loff);
        uint4 v2 = *(const uint4*)(h1b + (size_t)i2 * D + loff);
        uint4 v3 = *(const uint4*)(h1b + (size_t)i3 * D + loff);
        const uint32_t* w0 = (const uint32_t*)&v0;
        const uint32_t* w1 = (const uint32_t*)&v1;
        const uint32_t* w2 = (const uint32_t*)&v2;
        const uint32_t* w3 = (const uint32_t*)&v3;
#pragma unroll
        for (int q = 0; q < 4; q++) {
            acc[q * 2]     += b2f((uint16_t)w0[q]) + b2f((uint16_t)w1[q]) +
                              b2f((uint16_t)w2[q]) + b2f((uint16_t)w3[q]);
            acc[q * 2 + 1] += b2f((uint16_t)(w0[q] >> 16)) + b2f((uint16_t)(w1[q] >> 16)) +
                              b2f((uint16_t)(w2[q] >> 16)) + b2f((uint16_t)(w3[q] >> 16));
        }
    }
    for (; pos < end; pos++) {
        int i0 = es1[pos];
        uint4 v0 = *(const uint4*)(h1b + (size_t)i0 * D + loff);
        const uint32_t* w0 = (const uint32_t*)&v0;
#pragma unroll
        for (int q = 0; q < 4; q++) {
            acc[q * 2]     += b2f((uint16_t)w0[q]);
            acc[q * 2 + 1] += b2f((uint16_t)(w0[q] >> 16));
        }
    }

    union { uint4 u; unsigned short h[8]; } pk;
#pragma unroll
    for (int j = 0; j < 8; j++) pk.h[j] = (unsigned short)f2b(acc[j]);
    *(uint4*)(nbr + (size_t)d * D + loff) = pk.u;
}

// ---- epilogue GEMM, same pipeline (2 passes): out = h1b@wroot^T + nbr@wrel^T + brel ----
__global__ __launch_bounds__(256) void k_out2(const unsigned short* __restrict__ h1b,
                                              const unsigned short* __restrict__ nbr,
                                              const short* __restrict__ wroot_b,
                                              const short* __restrict__ wrel_b,
                                              const float* __restrict__ brel,
                                              float* __restrict__ out) {
    __shared__ short ws[2][128 * 128];
    int t = threadIdx.x;
    int wave = t >> 6, lane = t & 63, quad = lane >> 4, l16 = lane & 15;
    int arow_idx = blockIdx.x * 64 + wave * 16 + l16;
    int nodeC = arow_idx < N_NODES ? arow_idx : N_NODES - 1;
    int ci0 = wave * 8;

    const unsigned short* arow_s[2] = { h1b + (size_t)nodeC * D, nbr + (size_t)nodeC * D };
    const short* wb_s[2] = { wroot_b, wrel_b };

    uint4 aReg[2][4];
    {
        uint4 b0[8];
#pragma unroll
        for (int i = 0; i < 8; i++) {
            int row = (ci0 + i) * 4 + quad;
            b0[i] = *(const uint4*)(wroot_b + row * D + (l16 << 3));
        }
#pragma unroll
        for (int kc = 0; kc < 4; kc++) {
            aReg[0][kc] = *(const uint4*)(arow_s[0] + (kc * 4 + quad) * 8);
            aReg[1][kc] = *(const uint4*)(arow_s[1] + (kc * 4 + quad) * 8);
        }
#pragma unroll
        for (int i = 0; i < 8; i++) {
            int row = (ci0 + i) * 4 + quad;
            *(uint4*)&ws[0][row * 128 + ((l16 ^ (row & 15)) << 3)] = b0[i];
        }
    }
    __syncthreads();

    f32x4 acc[8];
#pragma unroll
    for (int jt = 0; jt < 8; jt++) acc[jt] = (f32x4){0.f, 0.f, 0.f, 0.f};

#pragma unroll
    for (int s = 0; s < 2; s++) {
        int cur = s & 1;
        uint4 bn[8];
        if (s == 0) {
#pragma unroll
            for (int i = 0; i < 8; i++) {
                int row = (ci0 + i) * 4 + quad;
                bn[i] = *(const uint4*)(wrel_b + row * D + (l16 << 3));
            }
        }
#pragma unroll
        for (int kc = 0; kc < 4; kc++) {
            int c0 = kc * 4 + quad;
            bf16x8 a = *(bf16x8*)&aReg[cur][kc];
#pragma unroll
            for (int jt = 0; jt < 8; jt++) {
                bf16x8 b = *(const bf16x8*)&ws[cur][(jt * 16 + l16) * 128 + ((c0 ^ l16) << 3)];
                acc[jt] = __builtin_amdgcn_mfma_f32_16x16x32_bf16(a, b, acc[jt], 0, 0, 0);
            }
        }
        if (s == 0) {
#pragma unroll
            for (int i = 0; i < 8; i++) {
                int row = (ci0 + i) * 4 + quad;
                *(uint4*)&ws[1][row * 128 + ((l16 ^ (row & 15)) << 3)] = bn[i];
            }
            __syncthreads();
        }
    }

#pragma unroll
    for (int reg = 0; reg < 4; reg++) {
        int node = blockIdx.x * 64 + wave * 16 + quad * 4 + reg;
        if (node >= N_NODES) continue;
#pragma unroll
        for (int jt = 0; jt < 8; jt++) {
            int col = jt * 16 + l16;
            out[(size_t)node * D + col] = acc[jt][reg] + brel[col];
        }
    }
}

extern "C" void kernel_launch(void* const* d_in, const int* in_sizes, int n_in,
                              void* d_out, int out_size, void* d_ws, size_t ws_size,
                              hipStream_t stream) {
    const float* x     = (const float*)d_in[0];
    const int*   ei    = (const int*)d_in[1];
    const int*   et    = (const int*)d_in[2];
    const float* basis = (const float*)d_in[3];
    const float* comp  = (const float*)d_in[4];
    const float* root  = (const float*)d_in[5];
    const float* bias1 = (const float*)d_in[6];
    const float* wrel  = (const float*)d_in[7];
    const float* brel  = (const float*)d_in[8];
    const float* wroot = (const float*)d_in[9];
    float* out = (float*)d_out;
    const int* src = ei;
    const int* dst = ei + E_EDGES;

    char* p = (char*)d_ws;
    auto alloc = [&](size_t bytes) { char* q = p; p += (bytes + 255) & ~(size_t)255; return q; };
    short* wt      = (short*)alloc((size_t)9 * D * D * sizeof(short));
    short* wrel_b  = (short*)alloc(D * D * sizeof(short));
    short* wroot_b = (short*)alloc(D * D * sizeof(short));
    int*   cntr    = (int*)alloc((size_t)RN * sizeof(int));
    int*   seg_off = (int*)alloc((size_t)RN * sizeof(int));
    int*   es1     = (int*)alloc((size_t)(E_EDGES + 16) * sizeof(int));
    int*   bsum    = (int*)alloc(1024 * sizeof(int));
    unsigned short* xb  = (unsigned short*)alloc((size_t)N_NODES * D * sizeof(unsigned short));
    unsigned short* mx  = (unsigned short*)alloc((size_t)RN * D * sizeof(unsigned short));
    unsigned short* h1b = (unsigned short*)alloc((size_t)N_NODES * D * sizeof(unsigned short));
    unsigned short* nbr = xb;   // xb dead after k_h1_gemm; reuse for nbr

    hipMemsetAsync(cntr, 0, (size_t)RN * sizeof(int), stream);

    const int XB_N = N_NODES * D / 8;
    int nfront = (XB_N + E_EDGES + 9 * D * D + D * D + 255) / 256;
    k_front<<<nfront, 256, 0, stream>>>(x, xb, dst, et, cntr,
                                        basis, comp, root, wrel, wroot,
                                        wt, wrel_b, wroot_b);

    int nscan = (RN + 1023) / 1024;   // 391
    k_scan_a<<<nscan, 1024, 0, stream>>>(cntr, seg_off, bsum, RN);
    k_scan_a<<<1, 1024, 0, stream>>>(bsum, bsum, nullptr, nscan);
    k_scan_c<<<nscan, 1024, 0, stream>>>(seg_off, bsum, RN);

    k_bucket<<<(E_EDGES + 255) / 256, 256, 0, stream>>>(src, dst, et, seg_off, es1);

    k_aggmean<<<RN / 16, 256, 0, stream>>>(xb, es1, seg_off, mx);

    int nb = (N_NODES + 63) / 64;     // 782
    int na = (N_NODES + 15) / 16;     // 3125
    k_h1_gemm<<<nb, 256, 0, stream>>>(mx, xb, wt, bias1, h1b);
    k_agg_nbr<<<na, 256, 0, stream>>>(h1b, es1, seg_off, nbr);
    k_out2<<<nb, 256, 0, stream>>>(h1b, nbr, wroot_b, wrel_b, brel, out);
}

// Round 10
// 264.664 us; speedup vs baseline: 1.5296x; 1.0325x over previous
//
#include <hip/hip_runtime.h>
#include <stdint.h>

#define N_NODES 50000
#define E_EDGES 600000
#define D 128
#define R_REL 8
#define B_BASES 10
#define RN (R_REL * N_NODES)

typedef __attribute__((ext_vector_type(8))) short bf16x8;
typedef __attribute__((ext_vector_type(4))) float f32x4;

__device__ __forceinline__ short f2b(float f) {
    uint32_t u = __float_as_uint(f);
    u += 0x7fff + ((u >> 16) & 1);   // RNE
    return (short)(u >> 16);
}
__device__ __forceinline__ float b2f(uint16_t u) {
    return __uint_as_float((uint32_t)u << 16);
}

// ---- front: x->bf16 convert + (dst,rel) histogram + weight prep, one launch ----
__global__ __launch_bounds__(256) void k_front(const float* __restrict__ x,
                                               unsigned short* __restrict__ xb,
                                               const int* __restrict__ dst,
                                               const int* __restrict__ et,
                                               int* __restrict__ cntr,
                                               const float* __restrict__ basis,
                                               const float* __restrict__ comp,
                                               const float* __restrict__ root,
                                               const float* __restrict__ wrel,
                                               const float* __restrict__ wroot,
                                               short* __restrict__ wt,
                                               short* __restrict__ wrel_b,
                                               short* __restrict__ wroot_b) {
    const int XB_N = N_NODES * D / 8;   // 800000
    int tid = blockIdx.x * 256 + threadIdx.x;
    if (tid < XB_N) {
        const float4* s = (const float4*)x + (size_t)tid * 2;
        float4 v0 = s[0], v1 = s[1];
        union { uint4 u; unsigned short h[8]; } pk;
        pk.h[0] = (unsigned short)f2b(v0.x); pk.h[1] = (unsigned short)f2b(v0.y);
        pk.h[2] = (unsigned short)f2b(v0.z); pk.h[3] = (unsigned short)f2b(v0.w);
        pk.h[4] = (unsigned short)f2b(v1.x); pk.h[5] = (unsigned short)f2b(v1.y);
        pk.h[6] = (unsigned short)f2b(v1.z); pk.h[7] = (unsigned short)f2b(v1.w);
        ((uint4*)xb)[tid] = pk.u;
    } else if (tid < XB_N + E_EDGES) {
        int e = tid - XB_N;
        atomicAdd(&cntr[dst[e] * R_REL + et[e]], 1);
    } else {
        int t2 = tid - XB_N - E_EDGES;
        if (t2 < 9 * D * D) {
            int s = t2 >> 14;
            int rem = t2 & 16383;
            int j = rem >> 7, i = rem & 127;
            float v;
            if (s < 8) {
                v = 0.f;
#pragma unroll
                for (int b = 0; b < B_BASES; b++)
                    v += comp[s * B_BASES + b] * basis[b * D * D + i * D + j];
            } else {
                v = root[i * D + j];
            }
            wt[t2] = f2b(v);
        } else {
            int t3 = t2 - 9 * D * D;
            if (t3 < D * D) {
                wrel_b[t3]  = f2b(wrel[t3]);
                wroot_b[t3] = f2b(wroot[t3]);
            }
        }
    }
}

// ---- shuffle-based block scan (1024 thr); doubles as level-2 when bsum==null ----
__device__ __forceinline__ int wave_scan_incl(int v) {
    int lane = threadIdx.x & 63;
#pragma unroll
    for (int off = 1; off < 64; off <<= 1) {
        int n = __shfl_up(v, off, 64);
        if (lane >= off) v += n;
    }
    return v;
}

__global__ __launch_bounds__(1024) void k_scan_a(const int* __restrict__ in,
                                                 int* __restrict__ out,
                                                 int* __restrict__ bsum, int n) {
    __shared__ int wsum[16];
    int t = threadIdx.x, lane = t & 63, wid = t >> 6;
    int g = blockIdx.x * 1024 + t;
    int v = (g < n) ? in[g] : 0;
    int isc = wave_scan_incl(v);
    if (lane == 63) wsum[wid] = isc;
    __syncthreads();
    if (wid == 0) {
        int wv = (lane < 16) ? wsum[lane] : 0;
        int wsc = wave_scan_incl(wv);
        if (lane < 16) wsum[lane] = wsc - wv;
    }
    __syncthreads();
    if (g < n) out[g] = wsum[wid] + isc - v;
    if (t == 1023 && bsum) bsum[blockIdx.x] = wsum[15] + isc;
}

__global__ __launch_bounds__(1024) void k_scan_c(int* __restrict__ out,
                                                 const int* __restrict__ bsum, int n) {
    int g = blockIdx.x * 1024 + threadIdx.x;
    if (g < n) out[g] += bsum[blockIdx.x];
}

// ---- bucket: es1[pos] = src, sorted by (dst,rel); bumps seg_off to segment ENDS ----
__global__ __launch_bounds__(256) void k_bucket(const int* __restrict__ src,
                                                const int* __restrict__ dst,
                                                const int* __restrict__ et,
                                                int* __restrict__ seg_off,
                                                int* __restrict__ es1) {
    int e = blockIdx.x * 256 + threadIdx.x;
    if (e >= E_EDGES) return;
    int key = dst[e] * R_REL + et[e];
    int pos = atomicAdd(&seg_off[key], 1);
    es1[pos] = src[e];
}

// ---- per-(dst,rel) mean of xb[src] -> mx bf16.  One 16-lane subwave / segment ----
__global__ __launch_bounds__(256) void k_aggmean(const unsigned short* __restrict__ xb,
                                                 const int* __restrict__ es1,
                                                 const int* __restrict__ seg_off,
                                                 unsigned short* __restrict__ mx) {
    int t = threadIdx.x;
    int sw = t >> 4, l = t & 15;
    int k = blockIdx.x * 16 + sw;
    if (k >= RN) return;
    int start = (k == 0) ? 0 : seg_off[k - 1];
    int end = seg_off[k];
    float ax[8];
#pragma unroll
    for (int q = 0; q < 8; q++) ax[q] = 0.f;
    size_t loff = (size_t)l * 8;
    int pos = start;
    for (; pos + 2 <= end; pos += 2) {
        int s0 = es1[pos], s1 = es1[pos + 1];
        uint4 v0 = *(const uint4*)(xb + (size_t)s0 * D + loff);
        uint4 v1 = *(const uint4*)(xb + (size_t)s1 * D + loff);
        const uint32_t* w0 = (const uint32_t*)&v0;
        const uint32_t* w1 = (const uint32_t*)&v1;
#pragma unroll
        for (int q = 0; q < 4; q++) {
            ax[q * 2]     += b2f((uint16_t)w0[q]) + b2f((uint16_t)w1[q]);
            ax[q * 2 + 1] += b2f((uint16_t)(w0[q] >> 16)) + b2f((uint16_t)(w1[q] >> 16));
        }
    }
    if (pos < end) {
        int s0 = es1[pos];
        uint4 v0 = *(const uint4*)(xb + (size_t)s0 * D + loff);
        const uint32_t* w0 = (const uint32_t*)&v0;
#pragma unroll
        for (int q = 0; q < 4; q++) {
            ax[q * 2]     += b2f((uint16_t)w0[q]);
            ax[q * 2 + 1] += b2f((uint16_t)(w0[q] >> 16));
        }
    }
    float nm = (end > start) ? 1.f / (float)(end - start) : 0.f;
    union { uint4 u; unsigned short h[8]; } pk;
#pragma unroll
    for (int q = 0; q < 8; q++) pk.h[q] = (unsigned short)f2b(ax[q] * nm);
    *(uint4*)(mx + (size_t)k * D + loff) = pk.u;   // k*128 = d*1024 + r*128
}

// ---- h1 GEMM, pipelined, M=32/wave (128 nodes/block): B dbuf LDS, A in regs ----
__global__ __launch_bounds__(256) void k_h1_gemm(const unsigned short* __restrict__ mx,
                                                 const unsigned short* __restrict__ xb,
                                                 const short* __restrict__ wt,
                                                 const float* __restrict__ bias1,
                                                 unsigned short* __restrict__ h1b) {
    __shared__ short ws[2][128 * 128];
    int t = threadIdx.x;
    int wave = t >> 6, lane = t & 63, quad = lane >> 4, l16 = lane & 15;
    int base = blockIdx.x * 128;
    int n0 = base + wave * 32 + l16;
    int n1 = n0 + 16;
    int nc0 = n0 < N_NODES ? n0 : N_NODES - 1;
    int nc1 = n1 < N_NODES ? n1 : N_NODES - 1;
    int ci0 = wave * 8;

    auto aptr = [&](int nc, int s) -> const unsigned short* {
        return (s < 8) ? mx + ((size_t)nc * 8 + s) * D : xb + (size_t)nc * D;
    };

    uint4 aReg[2][2][4];   // [parity][tile][kc]
    {
        uint4 b0[8];
#pragma unroll
        for (int i = 0; i < 8; i++) {
            int row = (ci0 + i) * 4 + quad;
            b0[i] = *(const uint4*)(wt + row * D + (l16 << 3));
        }
#pragma unroll
        for (int kc = 0; kc < 4; kc++) {
            int co = (kc * 4 + quad) * 8;
            aReg[0][0][kc] = *(const uint4*)(aptr(nc0, 0) + co);
            aReg[0][1][kc] = *(const uint4*)(aptr(nc1, 0) + co);
            aReg[1][0][kc] = *(const uint4*)(aptr(nc0, 1) + co);
            aReg[1][1][kc] = *(const uint4*)(aptr(nc1, 1) + co);
        }
#pragma unroll
        for (int i = 0; i < 8; i++) {
            int row = (ci0 + i) * 4 + quad;
            *(uint4*)&ws[0][row * 128 + ((l16 ^ (row & 15)) << 3)] = b0[i];
        }
    }
    __syncthreads();

    f32x4 acc[2][8];
#pragma unroll
    for (int tl = 0; tl < 2; tl++)
#pragma unroll
        for (int jt = 0; jt < 8; jt++) acc[tl][jt] = (f32x4){0.f, 0.f, 0.f, 0.f};

    for (int s = 0; s < 9; s++) {
        int cur = s & 1;
        uint4 bn[8];
        if (s + 1 < 9) {
            const short* wb = wt + (size_t)(s + 1) * D * D;
#pragma unroll
            for (int i = 0; i < 8; i++) {
                int row = (ci0 + i) * 4 + quad;
                bn[i] = *(const uint4*)(wb + row * D + (l16 << 3));
            }
        }
#pragma unroll
        for (int kc = 0; kc < 4; kc++) {
            int c0 = kc * 4 + quad;
            bf16x8 a0 = *(bf16x8*)&aReg[cur][0][kc];
            bf16x8 a1 = *(bf16x8*)&aReg[cur][1][kc];
#pragma unroll
            for (int jt = 0; jt < 8; jt++) {
                bf16x8 b = *(const bf16x8*)&ws[cur][(jt * 16 + l16) * 128 + ((c0 ^ l16) << 3)];
                acc[0][jt] = __builtin_amdgcn_mfma_f32_16x16x32_bf16(a0, b, acc[0][jt], 0, 0, 0);
                acc[1][jt] = __builtin_amdgcn_mfma_f32_16x16x32_bf16(a1, b, acc[1][jt], 0, 0, 0);
            }
        }
        if (s + 2 <= 8) {
#pragma unroll
            for (int kc = 0; kc < 4; kc++) {
                int co = (kc * 4 + quad) * 8;
                aReg[cur][0][kc] = *(const uint4*)(aptr(nc0, s + 2) + co);
                aReg[cur][1][kc] = *(const uint4*)(aptr(nc1, s + 2) + co);
            }
        }
        if (s + 1 < 9) {
#pragma unroll
            for (int i = 0; i < 8; i++) {
                int row = (ci0 + i) * 4 + quad;
                *(uint4*)&ws[cur ^ 1][row * 128 + ((l16 ^ (row & 15)) << 3)] = bn[i];
            }
        }
        __syncthreads();
    }

#pragma unroll
    for (int tl = 0; tl < 2; tl++) {
#pragma unroll
        for (int reg = 0; reg < 4; reg++) {
            int node = base + wave * 32 + tl * 16 + quad * 4 + reg;
            if (node >= N_NODES) continue;
#pragma unroll
            for (int jt = 0; jt < 8; jt++) {
                int col = jt * 16 + l16;
                float v = acc[tl][jt][reg] + bias1[col];
                h1b[(size_t)node * D + col] = (unsigned short)f2b(v);
            }
        }
    }
}

// ---- GraphConv agg: nbr[d] = sum h1b[src] over full in-edge range (16-lane subwave) ----
__global__ __launch_bounds__(256) void k_agg_nbr(const unsigned short* __restrict__ h1b,
                                                 const int* __restrict__ es1,
                                                 const int* __restrict__ seg_off,
                                                 unsigned short* __restrict__ nbr) {
    int t = threadIdx.x;
    int wave = t >> 6, lane = t & 63, sub = lane >> 4, l = lane & 15;
    int d = blockIdx.x * 16 + wave * 4 + sub;
    if (d >= N_NODES) return;
    int start = (d == 0) ? 0 : seg_off[d * R_REL - 1];
    int end = seg_off[d * R_REL + 7];
    float acc[8];
#pragma unroll
    for (int j = 0; j < 8; j++) acc[j] = 0.f;
    size_t loff = (size_t)l * 8;

    int pos = start;
    for (; pos + 4 <= end; pos += 4) {
        int i0 = es1[pos], i1 = es1[pos + 1], i2 = es1[pos + 2], i3 = es1[pos + 3];
        uint4 v0 = *(const uint4*)(h1b + (size_t)i0 * D + loff);
        uint4 v1 = *(const uint4*)(h1b + (size_t)i1 * D + loff);
        uint4 v2 = *(const uint4*)(h1b + (size_t)i2 * D + loff);
        uint4 v3 = *(const uint4*)(h1b + (size_t)i3 * D + loff);
        const uint32_t* w0 = (const uint32_t*)&v0;
        const uint32_t* w1 = (const uint32_t*)&v1;
        const uint32_t* w2 = (const uint32_t*)&v2;
        const uint32_t* w3 = (const uint32_t*)&v3;
#pragma unroll
        for (int q = 0; q < 4; q++) {
            acc[q * 2]     += b2f((uint16_t)w0[q]) + b2f((uint16_t)w1[q]) +
                              b2f((uint16_t)w2[q]) + b2f((uint16_t)w3[q]);
            acc[q * 2 + 1] += b2f((uint16_t)(w0[q] >> 16)) + b2f((uint16_t)(w1[q] >> 16)) +
                              b2f((uint16_t)(w2[q] >> 16)) + b2f((uint16_t)(w3[q] >> 16));
        }
    }
    for (; pos < end; pos++) {
        int i0 = es1[pos];
        uint4 v0 = *(const uint4*)(h1b + (size_t)i0 * D + loff);
        const uint32_t* w0 = (const uint32_t*)&v0;
#pragma unroll
        for (int q = 0; q < 4; q++) {
            acc[q * 2]     += b2f((uint16_t)w0[q]);
            acc[q * 2 + 1] += b2f((uint16_t)(w0[q] >> 16));
        }
    }

    union { uint4 u; unsigned short h[8]; } pk;
#pragma unroll
    for (int j = 0; j < 8; j++) pk.h[j] = (unsigned short)f2b(acc[j]);
    *(uint4*)(nbr + (size_t)d * D + loff) = pk.u;
}

// ---- epilogue GEMM, pipelined, M=32/wave: out = h1b@wroot^T + nbr@wrel^T + brel ----
__global__ __launch_bounds__(256) void k_out2(const unsigned short* __restrict__ h1b,
                                              const unsigned short* __restrict__ nbr,
                                              const short* __restrict__ wroot_b,
                                              const short* __restrict__ wrel_b,
                                              const float* __restrict__ brel,
                                              float* __restrict__ out) {
    __shared__ short ws[2][128 * 128];
    int t = threadIdx.x;
    int wave = t >> 6, lane = t & 63, quad = lane >> 4, l16 = lane & 15;
    int base = blockIdx.x * 128;
    int n0 = base + wave * 32 + l16;
    int n1 = n0 + 16;
    int nc0 = n0 < N_NODES ? n0 : N_NODES - 1;
    int nc1 = n1 < N_NODES ? n1 : N_NODES - 1;
    int ci0 = wave * 8;

    uint4 aReg[2][2][4];   // [pass][tile][kc]
    {
        uint4 b0[8];
#pragma unroll
        for (int i = 0; i < 8; i++) {
            int row = (ci0 + i) * 4 + quad;
            b0[i] = *(const uint4*)(wroot_b + row * D + (l16 << 3));
        }
#pragma unroll
        for (int kc = 0; kc < 4; kc++) {
            int co = (kc * 4 + quad) * 8;
            aReg[0][0][kc] = *(const uint4*)(h1b + (size_t)nc0 * D + co);
            aReg[0][1][kc] = *(const uint4*)(h1b + (size_t)nc1 * D + co);
            aReg[1][0][kc] = *(const uint4*)(nbr + (size_t)nc0 * D + co);
            aReg[1][1][kc] = *(const uint4*)(nbr + (size_t)nc1 * D + co);
        }
#pragma unroll
        for (int i = 0; i < 8; i++) {
            int row = (ci0 + i) * 4 + quad;
            *(uint4*)&ws[0][row * 128 + ((l16 ^ (row & 15)) << 3)] = b0[i];
        }
    }
    __syncthreads();

    f32x4 acc[2][8];
#pragma unroll
    for (int tl = 0; tl < 2; tl++)
#pragma unroll
        for (int jt = 0; jt < 8; jt++) acc[tl][jt] = (f32x4){0.f, 0.f, 0.f, 0.f};

#pragma unroll
    for (int s = 0; s < 2; s++) {
        int cur = s & 1;
        uint4 bn[8];
        if (s == 0) {
#pragma unroll
            for (int i = 0; i < 8; i++) {
                int row = (ci0 + i) * 4 + quad;
                bn[i] = *(const uint4*)(wrel_b + row * D + (l16 << 3));
            }
        }
#pragma unroll
        for (int kc = 0; kc < 4; kc++) {
            int c0 = kc * 4 + quad;
            bf16x8 a0 = *(bf16x8*)&aReg[cur][0][kc];
            bf16x8 a1 = *(bf16x8*)&aReg[cur][1][kc];
#pragma unroll
            for (int jt = 0; jt < 8; jt++) {
                bf16x8 b = *(const bf16x8*)&ws[cur][(jt * 16 + l16) * 128 + ((c0 ^ l16) << 3)];
                acc[0][jt] = __builtin_amdgcn_mfma_f32_16x16x32_bf16(a0, b, acc[0][jt], 0, 0, 0);
                acc[1][jt] = __builtin_amdgcn_mfma_f32_16x16x32_bf16(a1, b, acc[1][jt], 0, 0, 0);
            }
        }
        if (s == 0) {
#pragma unroll
            for (int i = 0; i < 8; i++) {
                int row = (ci0 + i) * 4 + quad;
                *(uint4*)&ws[1][row * 128 + ((l16 ^ (row & 15)) << 3)] = bn[i];
            }
            __syncthreads();
        }
    }

#pragma unroll
    for (int tl = 0; tl < 2; tl++) {
#pragma unroll
        for (int reg = 0; reg < 4; reg++) {
            int node = base + wave * 32 + tl * 16 + quad * 4 + reg;
            if (node >= N_NODES) continue;
#pragma unroll
            for (int jt = 0; jt < 8; jt++) {
                int col = jt * 16 + l16;
                out[(size_t)node * D + col] = acc[tl][jt][reg] + brel[col];
            }
        }
    }
}

extern "C" void kernel_launch(void* const* d_in, const int* in_sizes, int n_in,
                              void* d_out, int out_size, void* d_ws, size_t ws_size,
                              hipStream_t stream) {
    const float* x     = (const float*)d_in[0];
    const int*   ei    = (const int*)d_in[1];
    const int*   et    = (const int*)d_in[2];
    const float* basis = (const float*)d_in[3];
    const float* comp  = (const float*)d_in[4];
    const float* root  = (const float*)d_in[5];
    const float* bias1 = (const float*)d_in[6];
    const float* wrel  = (const float*)d_in[7];
    const float* brel  = (const float*)d_in[8];
    const float* wroot = (const float*)d_in[9];
    float* out = (float*)d_out;
    const int* src = ei;
    const int* dst = ei + E_EDGES;

    char* p = (char*)d_ws;
    auto alloc = [&](size_t bytes) { char* q = p; p += (bytes + 255) & ~(size_t)255; return q; };
    short* wt      = (short*)alloc((size_t)9 * D * D * sizeof(short));
    short* wrel_b  = (short*)alloc(D * D * sizeof(short));
    short* wroot_b = (short*)alloc(D * D * sizeof(short));
    int*   cntr    = (int*)alloc((size_t)RN * sizeof(int));
    int*   seg_off = (int*)alloc((size_t)RN * sizeof(int));
    int*   es1     = (int*)alloc((size_t)(E_EDGES + 16) * sizeof(int));
    int*   bsum    = (int*)alloc(1024 * sizeof(int));
    unsigned short* xb  = (unsigned short*)alloc((size_t)N_NODES * D * sizeof(unsigned short));
    unsigned short* mx  = (unsigned short*)alloc((size_t)RN * D * sizeof(unsigned short));
    unsigned short* h1b = (unsigned short*)alloc((size_t)N_NODES * D * sizeof(unsigned short));
    unsigned short* nbr = xb;   // xb dead after k_h1_gemm; reuse for nbr

    hipMemsetAsync(cntr, 0, (size_t)RN * sizeof(int), stream);

    const int XB_N = N_NODES * D / 8;
    int nfront = (XB_N + E_EDGES + 9 * D * D + D * D + 255) / 256;
    k_front<<<nfront, 256, 0, stream>>>(x, xb, dst, et, cntr,
                                        basis, comp, root, wrel, wroot,
                                        wt, wrel_b, wroot_b);

    int nscan = (RN + 1023) / 1024;   // 391
    k_scan_a<<<nscan, 1024, 0, stream>>>(cntr, seg_off, bsum, RN);
    k_scan_a<<<1, 1024, 0, stream>>>(bsum, bsum, nullptr, nscan);
    k_scan_c<<<nscan, 1024, 0, stream>>>(seg_off, bsum, RN);

    k_bucket<<<(E_EDGES + 255) / 256, 256, 0, stream>>>(src, dst, et, seg_off, es1);

    k_aggmean<<<RN / 16, 256, 0, stream>>>(xb, es1, seg_off, mx);

    int nb2 = (N_NODES + 127) / 128;  // 391
    int na = (N_NODES + 15) / 16;     // 3125
    k_h1_gemm<<<nb2, 256, 0, stream>>>(mx, xb, wt, bias1, h1b);
    k_agg_nbr<<<na, 256, 0, stream>>>(h1b, es1, seg_off, nbr);
    k_out2<<<nb2, 256, 0, stream>>>(h1b, nbr, wroot_b, wrel_b, brel, out);
}